// Round 4
// baseline (8101.110 us; speedup 1.0000x reference)
//
#include <hip/hip_runtime.h>

// ---------------------------------------------------------------------------
// 2-layer LSTM, S=512, B=64, I=H=1024 on MI355X.
//   * G0 = x@Wih0 + (bih0+bhh0) precomputed by bf16 MFMA GEMM into ws.
//   * Persistent rec_k (192 blocks, 1/CU): weights LDS-resident all chunk
//     steps (lane-linear swizzled, conflict-free). Blocks 0..63 = layer0
//     (Whh0, K=1024); 64..191 = layer1 ([Wih1;Whh1], K=2048, one step back).
//   * h0/h1 exchange buffers: ONE SLOT PER TIMESTEP (slot = t % CHUNK) ->
//     no acquire fence needed; consumers use plain cached loads (r2: -21%).
//   * Round 6 (poll de-congestion): per-step ARRIVAL COUNTERS replace the
//     per-block flag arrays. Producer: vmcnt(0) then one agent-scope
//     atomic_add to ctr[t] (own 64B line per step). Consumer: polls ONE
//     address (ctr==64/128) -- a same-address wave load = 1 line request.
//     The old scheme was a 64-line gather per spin x ~450 spinning waves
//     (~5 TB/s of pure polling LLC traffic, queuing ahead of every
//     latency-critical LLC access in the serial chain).
//   * Round 7: BUGFIX of round 6's workspace layout -- fixedSz was 512 B
//     short, so h0buf slot 0 aliased ctr1[504..511]: late-chunk polls read
//     bf16 h-data as counter values (pass early -> stale h1 reads) and
//     arrival adds corrupted h0. fixedSz now = end of ctr1 (34177024).
// ---------------------------------------------------------------------------

typedef unsigned short bhalf;
typedef __attribute__((ext_vector_type(8))) short s8v;    // 8 bf16 = 4 VGPRs
typedef __attribute__((ext_vector_type(4))) float f32x4;  // MFMA acc
typedef __attribute__((ext_vector_type(2))) unsigned int u32x2;

__device__ __forceinline__ float bf2f(bhalf u) {
    unsigned int x = ((unsigned int)u) << 16;
    return __builtin_bit_cast(float, x);
}
__device__ __forceinline__ bhalf f2bf(float f) {
    unsigned int x = __builtin_bit_cast(unsigned int, f);
    unsigned int r = (x + 0x7fffu + ((x >> 16) & 1u)) >> 16;
    return (bhalf)r;
}
__device__ __forceinline__ float sigf(float x) { return 1.f / (1.f + __expf(-x)); }
__device__ __forceinline__ float tanh_(float x) { return 2.f / (1.f + __expf(-2.f * x)) - 1.f; }

// relaxed agent-scope poll of one counter line (LLC-direct, 1 line/spin)
__device__ __forceinline__ void pollctr(const int* p, int need) {
    int it = 0;
    while (__hip_atomic_load(p, __ATOMIC_RELAXED, __HIP_MEMORY_SCOPE_AGENT) < need) {
        __builtin_amdgcn_s_sleep(1);
        if (++it > 50000000) break;  // safety: never hard-hang the bench
    }
}

// --------------------------- init (runs every call) -------------------------
__global__ __launch_bounds__(256) void init_k(
    const float* __restrict__ bih0, const float* __restrict__ bhh0,
    const float* __restrict__ bih1, const float* __restrict__ bhh1,
    float* bias0, float* bias1, bhalf* h0z, bhalf* h1z,
    float* c0, float* c1, int* ctrs)
{
    int i = blockIdx.x * 256 + threadIdx.x;  // grid 256 -> 65536 threads
    h0z[i] = 0; h1z[i] = 0; c0[i] = 0.f; c1[i] = 0.f;
    if (i < 16384) ctrs[i] = 0;              // ctr0[512*16] + ctr1[512*16]
    if (i < 4096) {
        bias0[i] = bih0[i] + bhh0[i];
        bias1[i] = bih1[i] + bhh1[i];
    }
}

// ---------------- transpose fp32 (1024 x 4096) -> bf16 [n][k] ----------------
__global__ __launch_bounds__(256) void transpose_k(
    const float* __restrict__ src, bhalf* __restrict__ dst, int dstStride, int kOff)
{
    __shared__ float T[64][65];
    int kb = blockIdx.x & 15;   // 1024/64
    int nb = blockIdx.x >> 4;   // 4096/64
    int k0 = kb << 6, n0 = nb << 6;
    int tid = threadIdx.x;
    #pragma unroll
    for (int i = 0; i < 16; ++i) {
        int lin = (i << 8) + tid;
        int r = lin >> 6, c = lin & 63;
        T[r][c] = src[(size_t)(k0 + r) * 4096 + n0 + c];
    }
    __syncthreads();
    #pragma unroll
    for (int i = 0; i < 16; ++i) {
        int lin = (i << 8) + tid;
        int r = lin >> 6, c = lin & 63;   // r = n-local, c = k-local
        dst[(size_t)(n0 + r) * dstStride + kOff + k0 + c] = f2bf(T[c][r]);
    }
}

// ------------- G0 GEMM: G0[row][n] = x[row]@Wih0 + bias0 (bf16 out) ----------
__global__ __launch_bounds__(256) void g0gemm_k(
    const float* __restrict__ x, const bhalf* __restrict__ WT,
    const float* __restrict__ bias0, bhalf* __restrict__ G0,
    int t0, int bmCount)
{
    __shared__ __align__(16) bhalf Xs[128 * 72];
    __shared__ __align__(16) bhalf Ws[128 * 72];
    const int tid = threadIdx.x;
    const int bm = blockIdx.x % bmCount;
    const int bn = blockIdx.x / bmCount;
    const int row0 = bm << 7;
    const int n0 = bn << 7;
    const int wid = tid >> 6, lane = tid & 63;
    const int wm = wid >> 1, wn = wid & 1;
    const int row16 = lane & 15, koff = (lane >> 4) << 3;

    f32x4 acc[4][4];
    const f32x4 zero4 = {0.f, 0.f, 0.f, 0.f};
    #pragma unroll
    for (int mt = 0; mt < 4; ++mt)
        #pragma unroll
        for (int nt = 0; nt < 4; ++nt) acc[mt][nt] = zero4;

    const float* xbase = x + (size_t)(t0 * 64 + row0) * 1024;
    for (int kc = 0; kc < 16; ++kc) {
        __syncthreads();
        #pragma unroll
        for (int j = 0; j < 8; ++j) {               // stage X: 128x64 fp32 -> bf16
            int e = (((j << 8) + tid) << 2);
            int r = e >> 6, k = e & 63;
            f32x4 xv = *(const f32x4*)(xbase + (size_t)r * 1024 + (kc << 6) + k);
            u32x2 p;
            p.x = (unsigned)f2bf(xv.x) | ((unsigned)f2bf(xv.y) << 16);
            p.y = (unsigned)f2bf(xv.z) | ((unsigned)f2bf(xv.w) << 16);
            *(u32x2*)&Xs[r * 72 + k] = p;
        }
        #pragma unroll
        for (int j = 0; j < 4; ++j) {               // stage W rows [n][k]
            int e = (((j << 8) + tid) << 3);
            int r = e >> 6, k = e & 63;
            *(s8v*)&Ws[r * 72 + k] = *(const s8v*)(WT + (size_t)(n0 + r) * 1024 + (kc << 6) + k);
        }
        __syncthreads();
        #pragma unroll
        for (int ks = 0; ks < 2; ++ks) {
            int kk = ks << 5;
            s8v a[4], b[4];
            #pragma unroll
            for (int mt = 0; mt < 4; ++mt)
                a[mt] = *(const s8v*)&Xs[(wm * 64 + mt * 16 + row16) * 72 + kk + koff];
            #pragma unroll
            for (int nt = 0; nt < 4; ++nt)
                b[nt] = *(const s8v*)&Ws[(wn * 64 + nt * 16 + row16) * 72 + kk + koff];
            #pragma unroll
            for (int mt = 0; mt < 4; ++mt)
                #pragma unroll
                for (int nt = 0; nt < 4; ++nt)
                    acc[mt][nt] = __builtin_amdgcn_mfma_f32_16x16x32_bf16(a[mt], b[nt], acc[mt][nt], 0, 0, 0);
        }
    }
    #pragma unroll
    for (int mt = 0; mt < 4; ++mt)
        #pragma unroll
        for (int nt = 0; nt < 4; ++nt) {
            int gcol = n0 + wn * 64 + nt * 16 + row16;
            float bz = bias0[gcol];
            #pragma unroll
            for (int r = 0; r < 4; ++r) {
                int grow = row0 + wm * 64 + mt * 16 + ((lane >> 4) << 2) + r;
                G0[((size_t)grow << 12) + gcol] = f2bf(acc[mt][nt][r] + bz);
            }
        }
}

// --------------------------- persistent recurrence ---------------------------
template <bool IS_L0>
__device__ __forceinline__ void rec_loop(
    const bhalf* Wlds, float* gatesLds,
    const bhalf* __restrict__ G0, const float* __restrict__ bias1,
    bhalf* h0buf, bhalf* h1buf, float* cws,
    int* ctr0, int* ctr1, float* out,
    int t0, int nsteps, int smask, int wgIdx)
{
    constexpr int NMT = IS_L0 ? 4 : 2;     // 16-wide gate-col tiles
    constexpr int NH  = IS_L0 ? 16 : 8;    // h-cols per WG
    const int tid = threadIdx.x;
    const int wid = tid >> 6, lane = tid & 63;
    const int row16 = lane & 15;
    const int koff = (lane >> 4) << 3;
    const int hcBase = wgIdx * NH;
    const f32x4 zero4 = {0.f, 0.f, 0.f, 0.f};

    // epilogue geometry: 4 adjacent h-cols per thread
    const bool ep_active = IS_L0 ? true : (tid < 128);
    const int eb  = IS_L0 ? (tid >> 2) : (tid >> 1);
    const int ejq = (IS_L0 ? (tid & 3) : (tid & 1)) << 2;
    const int ehc = hcBase + ejq;

    float creg[4] = {0.f, 0.f, 0.f, 0.f};
    float breg[4][4];
    if (ep_active) {
        #pragma unroll
        for (int j = 0; j < 4; ++j) creg[j] = cws[(eb << 10) + ehc + j];
        if (!IS_L0)
            #pragma unroll
            for (int g = 0; g < 4; ++g)
                #pragma unroll
                for (int j = 0; j < 4; ++j) breg[g][j] = bias1[(g << 10) + ehc + j];
    }
    int* myctr = IS_L0 ? ctr0 : ctr1;

    for (int tl = 0; tl < nsteps; ++tl) {
        const int t = t0 + tl;

        // prefetch G0 for this step BEFORE polling (chunk-static data)
        u32x2 g0pre[4];
        if (IS_L0) {
            const bhalf* gp = G0 + (((size_t)tl * 64 + eb) << 12) + ehc;
            #pragma unroll
            for (int g = 0; g < 4; ++g) g0pre[g] = *(const u32x2*)(gp + (g << 10));
        }

        // counter semantics: ctr0[t]==64  <=> h0(t) fully published;
        //                    ctr1[t]==128 <=> h1(t) fully published.
        // One address per poll; 64-lane same-address load = 1 line request.
        if (IS_L0) {
            if (wid == 0 && t > 0) pollctr(&ctr0[(t - 1) << 4], 64);
        } else {
            if (wid == 0)               pollctr(&ctr0[t << 4], 64);
            else if (wid == 1 && t > 0) pollctr(&ctr1[(t - 1) << 4], 128);
        }
        __syncthreads();
        // NO acquire fence: h slots are write-once/read-after-poll within this
        // dispatch, so plain cached loads can never observe stale data.

        const int prev = (tl - 1) & smask;
        const bhalf* h0r = h0buf + ((size_t)prev << 16);  // h0(t-1)
        const bhalf* h0c = h0buf + ((size_t)tl << 16);    // h0(t)
        const bhalf* h1r = h1buf + ((size_t)prev << 16);  // h1(t-1)
        const int brow = (wid << 4) + row16;              // batch row (wave-split)

        f32x4 acc[NMT];
        #pragma unroll
        for (int mt = 0; mt < NMT; ++mt) acc[mt] = zero4;

        if (IS_L0) {
            // bulk-load all 32 B-frags (L2-shared within the XCD), then MFMA
            s8v bfr[32];
            #pragma unroll
            for (int ks = 0; ks < 32; ++ks)
                bfr[ks] = *(const s8v*)(h0r + brow * 1024 + (ks << 5) + koff);
            #pragma unroll
            for (int ks = 0; ks < 32; ++ks)
                #pragma unroll
                for (int mt = 0; mt < 4; ++mt) {
                    s8v a = *(const s8v*)&Wlds[((((mt << 5) + ks) << 6) + lane) << 3];
                    acc[mt] = __builtin_amdgcn_mfma_f32_16x16x32_bf16(a, bfr[ks], acc[mt], 0, 0, 0);
                }
        } else {
            // pass0: k 0..1023 from h0(t); pass1: k 1024..2047 from h1(t-1)
            s8v bfa[32], bfb[32];
            #pragma unroll
            for (int ks = 0; ks < 32; ++ks)
                bfa[ks] = *(const s8v*)(h0c + brow * 1024 + (ks << 5) + koff);
            #pragma unroll
            for (int ks = 0; ks < 32; ++ks)
                bfb[ks] = *(const s8v*)(h1r + brow * 1024 + (ks << 5) + koff);
            #pragma unroll
            for (int ks = 0; ks < 32; ++ks)
                #pragma unroll
                for (int mt = 0; mt < 2; ++mt) {
                    s8v a = *(const s8v*)&Wlds[((((mt << 6) + ks) << 6) + lane) << 3];
                    acc[mt] = __builtin_amdgcn_mfma_f32_16x16x32_bf16(a, bfa[ks], acc[mt], 0, 0, 0);
                }
            #pragma unroll
            for (int ks = 0; ks < 32; ++ks)
                #pragma unroll
                for (int mt = 0; mt < 2; ++mt) {
                    s8v a = *(const s8v*)&Wlds[((((mt << 6) + 32 + ks) << 6) + lane) << 3];
                    acc[mt] = __builtin_amdgcn_mfma_f32_16x16x32_bf16(a, bfb[ks], acc[mt], 0, 0, 0);
                }
        }
        #pragma unroll
        for (int mt = 0; mt < NMT; ++mt)
            #pragma unroll
            for (int r = 0; r < 4; ++r) {
                int ci = (mt << 4) + ((lane >> 4) << 2) + r;  // gate-col local
                gatesLds[ci * 68 + brow] = acc[mt][r];
            }
        __syncthreads();

        // epilogue: 4 adjacent h-cols per thread, 8B packed h publish
        float hv[4] = {0.f, 0.f, 0.f, 0.f};
        if (ep_active) {
            float ga[4][4];
            #pragma unroll
            for (int g = 0; g < 4; ++g)
                #pragma unroll
                for (int j = 0; j < 4; ++j)
                    ga[g][j] = gatesLds[(g * NH + ejq + j) * 68 + eb];
            if (IS_L0) {
                #pragma unroll
                for (int g = 0; g < 4; ++g) {
                    ga[g][0] += bf2f((bhalf)(g0pre[g].x & 0xffffu));
                    ga[g][1] += bf2f((bhalf)(g0pre[g].x >> 16));
                    ga[g][2] += bf2f((bhalf)(g0pre[g].y & 0xffffu));
                    ga[g][3] += bf2f((bhalf)(g0pre[g].y >> 16));
                }
            } else {
                #pragma unroll
                for (int g = 0; g < 4; ++g)
                    #pragma unroll
                    for (int j = 0; j < 4; ++j) ga[g][j] += breg[g][j];
            }
            #pragma unroll
            for (int j = 0; j < 4; ++j) {
                float cn = sigf(ga[1][j]) * creg[j] + sigf(ga[0][j]) * tanh_(ga[3][j]);
                creg[j] = cn;
                hv[j] = sigf(ga[2][j]) * tanh_(cn);
            }
            u32x2 hp;
            hp.x = (unsigned)f2bf(hv[0]) | ((unsigned)f2bf(hv[1]) << 16);
            hp.y = (unsigned)f2bf(hv[2]) | ((unsigned)f2bf(hv[3]) << 16);
            unsigned long long hpu = __builtin_bit_cast(unsigned long long, hp);
            const int ix = (eb << 10) + ehc;
            bhalf* hdst = (IS_L0 ? h0buf : h1buf) + ((size_t)tl << 16) + ix;
            __hip_atomic_store((unsigned long long*)hdst, hpu,
                               __ATOMIC_RELAXED, __HIP_MEMORY_SCOPE_AGENT);
        }
        // publish: all h stores acked at the LLC, then ONE atomic arrival
        asm volatile("s_waitcnt vmcnt(0)" ::: "memory");
        __syncthreads();
        if (tid == 0)
            __hip_atomic_fetch_add(&myctr[t << 4], 1,
                                   __ATOMIC_RELAXED, __HIP_MEMORY_SCOPE_AGENT);
        // `out` is only read by the host at the end: issue its HBM stores
        // AFTER the arrival so their write-ack is off the critical path
        if (!IS_L0 && ep_active) {
            f32x4 ov = {hv[0], hv[1], hv[2], hv[3]};
            *(f32x4*)(out + (((size_t)t * 64 + eb) << 10) + ehc) = ov;
        }
    }

    // persist c for next chunk / tail
    if (ep_active) {
        #pragma unroll
        for (int j = 0; j < 4; ++j) cws[(eb << 10) + ehc + j] = creg[j];
    }
}

__global__ __launch_bounds__(256, 1) void rec_k(
    const bhalf* __restrict__ W0T, const bhalf* __restrict__ W1T,
    const bhalf* __restrict__ G0, const float* __restrict__ bias1,
    bhalf* h0buf, bhalf* h1buf, float* c0ws, float* c1ws,
    int* ctr0, int* ctr1, float* out, int t0, int nsteps, int smask)
{
    __shared__ __align__(16) bhalf Wlds[65536];        // 128 KB swizzled weights
    __shared__ __align__(16) float gatesLds[64 * 68];  // 17 KB gate exchange
    const int tid = threadIdx.x;
    const int wg = blockIdx.x;
    if (wg < 64) {
        // layer0: 64 gate-cols (16 h-cols); swizzle to lane-linear frag order
        for (int it = 0; it < 32; ++it) {
            int e = (((it << 8) + tid) << 3);
            int ci = e >> 10, k0 = e & 1023;
            int n = ((ci >> 4) << 10) + (wg << 4) + (ci & 15);
            int mt = ci >> 4, m = ci & 15, ks = k0 >> 5, q = (k0 >> 3) & 3;
            int off = ((((mt << 5) + ks) << 6) + (q << 4) + m) << 3;
            *(s8v*)&Wlds[off] = *(const s8v*)(W0T + ((size_t)n << 10) + k0);
        }
        __syncthreads();
        rec_loop<true>(Wlds, gatesLds, G0, bias1, h0buf, h1buf, c0ws,
                       ctr0, ctr1, out, t0, nsteps, smask, wg);
    } else {
        int wg1 = wg - 64;
        // layer1: 32 gate-cols (8 h-cols), K=2048
        for (int it = 0; it < 32; ++it) {
            int e = (((it << 8) + tid) << 3);
            int ci = e >> 11, k0 = e & 2047;
            int n = ((ci >> 3) << 10) + (wg1 << 3) + (ci & 7);
            int mt = ci >> 4, m = ci & 15, ks = k0 >> 5, q = (k0 >> 3) & 3;
            int off = ((((mt << 6) + ks) << 6) + (q << 4) + m) << 3;
            *(s8v*)&Wlds[off] = *(const s8v*)(W1T + ((size_t)n << 11) + k0);
        }
        __syncthreads();
        rec_loop<false>(Wlds, gatesLds, G0, bias1, h0buf, h1buf, c1ws,
                        ctr0, ctr1, out, t0, nsteps, smask, wg1);
    }
}

// --------------------------------- tail -------------------------------------
__global__ __launch_bounds__(256) void tail_k(
    const bhalf* __restrict__ h0f, const bhalf* __restrict__ h1f,
    const float* __restrict__ c0, const float* __restrict__ c1, float* dst)
{
    int i = blockIdx.x * 256 + threadIdx.x;  // grid 512 -> 131072
    if (i >= 131072) return;
    int l = i >> 16, r = i & 65535;
    dst[i] = bf2f(l ? h1f[r] : h0f[r]);
    dst[131072 + i] = l ? c1[r] : c0[r];
}

// --------------------------------- host -------------------------------------
extern "C" void kernel_launch(void* const* d_in, const int* in_sizes, int n_in,
                              void* d_out, int out_size, void* d_ws, size_t ws_size,
                              hipStream_t stream) {
    const float* x    = (const float*)d_in[0];
    const float* Wih0 = (const float*)d_in[1];
    const float* bih0 = (const float*)d_in[2];
    const float* Whh0 = (const float*)d_in[3];
    const float* bhh0 = (const float*)d_in[4];
    const float* Wih1 = (const float*)d_in[5];
    const float* bih1 = (const float*)d_in[6];
    const float* Whh1 = (const float*)d_in[7];
    const float* bhh1 = (const float*)d_in[8];
    float* out = (float*)d_out;
    char* ws = (char*)d_ws;

    bhalf* WT0ih = (bhalf*)(ws);                    // [4096][1024] bf16
    bhalf* WT0hh = (bhalf*)(ws + 8388608);          // [4096][1024]
    bhalf* WT1   = (bhalf*)(ws + 16777216);         // [4096][2048] = [Wih1;Whh1]
    float* bias0 = (float*)(ws + 33554432);
    float* bias1 = (float*)(ws + 33570816);
    float* c0    = (float*)(ws + 33587200);         // 64x1024 f32
    float* c1    = (float*)(ws + 33849344);
    int*   ctr0  = (int*)(ws + 34111488);           // 512 x 16 ints, ends 34144256
    int*   ctr1  = (int*)(ws + 34144256);           // 512 x 16 ints, ends 34177024
    const size_t fixedSz = 34177024;                // = end of ctr1 (r3 bug: was 512 B short)

    // per-step h slots: h0/h1 each CHUNK x 128KB; G0 CHUNK x 512KB
    int CHUNK = 8;
    for (int c = 512; c >= 8; c >>= 1)
        if (fixedSz + (size_t)c * (131072 + 131072 + 524288) <= ws_size) { CHUNK = c; break; }

    bhalf* h0buf = (bhalf*)(ws + fixedSz);
    bhalf* h1buf = (bhalf*)(ws + fixedSz + (size_t)CHUNK * 131072);
    bhalf* G0    = (bhalf*)(ws + fixedSz + (size_t)CHUNK * 262144);

    // zero the incoming-state slot (slot CHUNK-1 holds h(t0-1) at chunk start;
    // for t0=0 that must be zeros)
    init_k<<<256, 256, 0, stream>>>(bih0, bhh0, bih1, bhh1, bias0, bias1,
                                    h0buf + (size_t)(CHUNK - 1) * 65536,
                                    h1buf + (size_t)(CHUNK - 1) * 65536,
                                    c0, c1, ctr0);
    transpose_k<<<1024, 256, 0, stream>>>(Wih0, WT0ih, 1024, 0);
    transpose_k<<<1024, 256, 0, stream>>>(Whh0, WT0hh, 1024, 0);
    transpose_k<<<1024, 256, 0, stream>>>(Wih1, WT1, 2048, 0);
    transpose_k<<<1024, 256, 0, stream>>>(Whh1, WT1, 2048, 1024);

    for (int t0 = 0; t0 < 512; t0 += CHUNK) {
        int bmCount = CHUNK / 2;
        g0gemm_k<<<bmCount * 32, 256, 0, stream>>>(x, WT0ih, bias0, G0, t0, bmCount);
        rec_k<<<192, 256, 0, stream>>>(WT0hh, WT1, G0, bias1, h0buf, h1buf,
                                       c0, c1, ctr0, ctr1, out, t0, CHUNK, CHUNK - 1);
    }
    // final h: t=511 -> slot 511 % CHUNK == CHUNK-1 (512 is a multiple of CHUNK)
    tail_k<<<512, 256, 0, stream>>>(h0buf + (size_t)(CHUNK - 1) * 65536,
                                    h1buf + (size_t)(CHUNK - 1) * 65536,
                                    c0, c1, out + 33554432);
}

// Round 5
// 7332.898 us; speedup vs baseline: 1.1048x; 1.1048x over previous
//
#include <hip/hip_runtime.h>

// ---------------------------------------------------------------------------
// 2-layer LSTM, S=512, B=64, I=H=1024 on MI355X.
//   * G0 = x@Wih0 + (bih0+bhh0) precomputed by bf16 MFMA GEMM into ws.
//   * Persistent rec_k (192 blocks, 1/CU): weights LDS-resident (lane-linear
//     swizzled). Blocks 0..63 = layer0 (Whh0, K=1024); 64..191 = layer1
//     ([Wih1;Whh1], K=2048, one step behind).
//   * h0/h1 exchange: ONE SLOT PER TIMESTEP -> no acquire fence, plain
//     cached loads (r2: -21%).
//   * Sync: r2's spread per-block flags (128B apart). r4 taught us: a shared
//     arrival counter serializes 64-128 RMWs on one LLC line and consumers'
//     polls contend with them -> slower. Spread flags win.
//   * Round 8 (register epilogue): the MFMA C-layout (col=lane&15=batch,
//     row=(lane>>4)*4+r=W-row) + gate-major W staging means each lane
//     ALREADY holds all 4 gates of its h-cols in acc[][]: L0 acc[g][r] =
//     gate g of h-col wg*16+q*4+r. The LDS gate exchange (write+barrier+
//     read+128-thread epilogue) was pure critical-path overhead -- removed.
//     L1 W1 rows re-permuted (n = g*1024+wg*8+hc; mt=g&1, m=2*hc+(g>>1)) so
//     lane q holds all 4 gates of h-cols wg*8+q*2..+1 in acc[0..1][0..3].
//     Cell update + h publish now fully per-lane, all 4 waves in parallel,
//     one barrier fewer per step. (Chip runs ~1 GHz under this 95%-idle
//     load -- MfmaUtil 4.9% vs 2% predicted at 2.4 GHz -- so every removed
//     serial leg counts ~2.4x.)
// ---------------------------------------------------------------------------

typedef unsigned short bhalf;
typedef __attribute__((ext_vector_type(8))) short s8v;    // 8 bf16 = 4 VGPRs
typedef __attribute__((ext_vector_type(4))) float f32x4;  // MFMA acc
typedef __attribute__((ext_vector_type(2))) float f32x2;
typedef __attribute__((ext_vector_type(2))) unsigned int u32x2;

__device__ __forceinline__ float bf2f(bhalf u) {
    unsigned int x = ((unsigned int)u) << 16;
    return __builtin_bit_cast(float, x);
}
__device__ __forceinline__ bhalf f2bf(float f) {
    unsigned int x = __builtin_bit_cast(unsigned int, f);
    unsigned int r = (x + 0x7fffu + ((x >> 16) & 1u)) >> 16;
    return (bhalf)r;
}
__device__ __forceinline__ float sigf(float x) { return 1.f / (1.f + __expf(-x)); }
__device__ __forceinline__ float tanh_(float x) { return 2.f / (1.f + __expf(-2.f * x)) - 1.f; }
// unpack element r (0..3) of a 4x bf16 pair-packed u32x2
__device__ __forceinline__ float g0elem(u32x2 p, int r) {
    unsigned u = (r & 2) ? p.y : p.x;
    return bf2f((bhalf)((r & 1) ? (u >> 16) : (u & 0xffffu)));
}

// relaxed agent-scope poll: LLC-direct load, no cache maintenance per spin
__device__ __forceinline__ void pollge(const int* p, int target) {
    if (target <= 0) return;
    int it = 0;
    while (__hip_atomic_load(p, __ATOMIC_RELAXED, __HIP_MEMORY_SCOPE_AGENT) < target) {
        __builtin_amdgcn_s_sleep(1);
        if (++it > 50000000) break;  // safety: never hard-hang the bench
    }
}

// --------------------------- init (runs every call) -------------------------
__global__ __launch_bounds__(256) void init_k(
    const float* __restrict__ bih0, const float* __restrict__ bhh0,
    const float* __restrict__ bih1, const float* __restrict__ bhh1,
    float* bias0, float* bias1, bhalf* h0z, bhalf* h1z,
    float* c0, float* c1, int* flags)
{
    int i = blockIdx.x * 256 + threadIdx.x;  // grid 256 -> 65536 threads
    h0z[i] = 0; h1z[i] = 0; c0[i] = 0.f; c1[i] = 0.f;
    if (i < 6144) flags[i] = 0;              // done0[64*32] + done1[128*32]
    if (i < 4096) {
        bias0[i] = bih0[i] + bhh0[i];
        bias1[i] = bih1[i] + bhh1[i];
    }
}

// ---------------- transpose fp32 (1024 x 4096) -> bf16 [n][k] ----------------
__global__ __launch_bounds__(256) void transpose_k(
    const float* __restrict__ src, bhalf* __restrict__ dst, int dstStride, int kOff)
{
    __shared__ float T[64][65];
    int kb = blockIdx.x & 15;   // 1024/64
    int nb = blockIdx.x >> 4;   // 4096/64
    int k0 = kb << 6, n0 = nb << 6;
    int tid = threadIdx.x;
    #pragma unroll
    for (int i = 0; i < 16; ++i) {
        int lin = (i << 8) + tid;
        int r = lin >> 6, c = lin & 63;
        T[r][c] = src[(size_t)(k0 + r) * 4096 + n0 + c];
    }
    __syncthreads();
    #pragma unroll
    for (int i = 0; i < 16; ++i) {
        int lin = (i << 8) + tid;
        int r = lin >> 6, c = lin & 63;   // r = n-local, c = k-local
        dst[(size_t)(n0 + r) * dstStride + kOff + k0 + c] = f2bf(T[c][r]);
    }
}

// ------------- G0 GEMM: G0[row][n] = x[row]@Wih0 + bias0 (bf16 out) ----------
__global__ __launch_bounds__(256) void g0gemm_k(
    const float* __restrict__ x, const bhalf* __restrict__ WT,
    const float* __restrict__ bias0, bhalf* __restrict__ G0,
    int t0, int bmCount)
{
    __shared__ __align__(16) bhalf Xs[128 * 72];
    __shared__ __align__(16) bhalf Ws[128 * 72];
    const int tid = threadIdx.x;
    const int bm = blockIdx.x % bmCount;
    const int bn = blockIdx.x / bmCount;
    const int row0 = bm << 7;
    const int n0 = bn << 7;
    const int wid = tid >> 6, lane = tid & 63;
    const int wm = wid >> 1, wn = wid & 1;
    const int row16 = lane & 15, koff = (lane >> 4) << 3;

    f32x4 acc[4][4];
    const f32x4 zero4 = {0.f, 0.f, 0.f, 0.f};
    #pragma unroll
    for (int mt = 0; mt < 4; ++mt)
        #pragma unroll
        for (int nt = 0; nt < 4; ++nt) acc[mt][nt] = zero4;

    const float* xbase = x + (size_t)(t0 * 64 + row0) * 1024;
    for (int kc = 0; kc < 16; ++kc) {
        __syncthreads();
        #pragma unroll
        for (int j = 0; j < 8; ++j) {               // stage X: 128x64 fp32 -> bf16
            int e = (((j << 8) + tid) << 2);
            int r = e >> 6, k = e & 63;
            f32x4 xv = *(const f32x4*)(xbase + (size_t)r * 1024 + (kc << 6) + k);
            u32x2 p;
            p.x = (unsigned)f2bf(xv.x) | ((unsigned)f2bf(xv.y) << 16);
            p.y = (unsigned)f2bf(xv.z) | ((unsigned)f2bf(xv.w) << 16);
            *(u32x2*)&Xs[r * 72 + k] = p;
        }
        #pragma unroll
        for (int j = 0; j < 4; ++j) {               // stage W rows [n][k]
            int e = (((j << 8) + tid) << 3);
            int r = e >> 6, k = e & 63;
            *(s8v*)&Ws[r * 72 + k] = *(const s8v*)(WT + (size_t)(n0 + r) * 1024 + (kc << 6) + k);
        }
        __syncthreads();
        #pragma unroll
        for (int ks = 0; ks < 2; ++ks) {
            int kk = ks << 5;
            s8v a[4], b[4];
            #pragma unroll
            for (int mt = 0; mt < 4; ++mt)
                a[mt] = *(const s8v*)&Xs[(wm * 64 + mt * 16 + row16) * 72 + kk + koff];
            #pragma unroll
            for (int nt = 0; nt < 4; ++nt)
                b[nt] = *(const s8v*)&Ws[(wn * 64 + nt * 16 + row16) * 72 + kk + koff];
            #pragma unroll
            for (int mt = 0; mt < 4; ++mt)
                #pragma unroll
                for (int nt = 0; nt < 4; ++nt)
                    acc[mt][nt] = __builtin_amdgcn_mfma_f32_16x16x32_bf16(a[mt], b[nt], acc[mt][nt], 0, 0, 0);
        }
    }
    #pragma unroll
    for (int mt = 0; mt < 4; ++mt)
        #pragma unroll
        for (int nt = 0; nt < 4; ++nt) {
            int gcol = n0 + wn * 64 + nt * 16 + row16;
            float bz = bias0[gcol];
            #pragma unroll
            for (int r = 0; r < 4; ++r) {
                int grow = row0 + wm * 64 + mt * 16 + ((lane >> 4) << 2) + r;
                G0[((size_t)grow << 12) + gcol] = f2bf(acc[mt][nt][r] + bz);
            }
        }
}

// --------------------------- persistent recurrence ---------------------------
template <bool IS_L0>
__device__ __forceinline__ void rec_loop(
    const bhalf* Wlds,
    const bhalf* __restrict__ G0, const float* __restrict__ bias1,
    bhalf* h0buf, bhalf* h1buf, float* cws,
    int* done0, int* done1, float* out,
    int t0, int nsteps, int smask, int wgIdx)
{
    constexpr int NMT = IS_L0 ? 4 : 2;   // 16-wide W-row tiles
    constexpr int NC  = IS_L0 ? 4 : 2;   // h-cols per lane
    const int tid = threadIdx.x;
    const int wid = tid >> 6, lane = tid & 63;
    const int row16 = lane & 15;
    const int q = lane >> 4;
    const int koff = q << 3;
    const int batch = (wid << 4) + row16;                  // C col = batch row
    const int myhc = IS_L0 ? ((wgIdx << 4) + (q << 2))     // lane-owned h-cols
                           : ((wgIdx << 3) + (q << 1));
    const f32x4 zero4 = {0.f, 0.f, 0.f, 0.f};

    // per-lane recurrent state (c) and bias
    float creg[NC];
    {
        const float* cp = cws + ((size_t)batch << 10) + myhc;
        #pragma unroll
        for (int j = 0; j < NC; ++j) creg[j] = cp[j];
    }
    float breg[4][2];
    if (!IS_L0) {
        #pragma unroll
        for (int g = 0; g < 4; ++g) {
            f32x2 b2 = *(const f32x2*)(bias1 + (g << 10) + myhc);
            breg[g][0] = b2.x; breg[g][1] = b2.y;
        }
    }
    int* myflag = IS_L0 ? &done0[wgIdx * 32] : &done1[wgIdx * 32];

    for (int tl = 0; tl < nsteps; ++tl) {
        const int t = t0 + tl;

        // prefetch G0 for this step BEFORE polling (chunk-static data)
        u32x2 g0pre[4];
        if (IS_L0) {
            const bhalf* gp = G0 + (((size_t)tl * 64 + batch) << 12) + myhc;
            #pragma unroll
            for (int g = 0; g < 4; ++g) g0pre[g] = *(const u32x2*)(gp + (g << 10));
        }

        // flag semantics: done[b] == s+1  <=>  block b finished step s
        if (IS_L0) {
            if (wid == 0) pollge(&done0[lane * 32], t);
        } else {
            if (wid == 0)      pollge(&done0[lane * 32], t + 1);
            else if (wid == 1) pollge(&done1[lane * 32], t);
            else if (wid == 2) pollge(&done1[(64 + lane) * 32], t);
        }
        __syncthreads();
        // NO acquire fence: h slots are write-once/read-after-poll within this
        // dispatch, so plain cached loads can never observe stale data.

        const int prev = (tl - 1) & smask;
        const bhalf* h0r = h0buf + ((size_t)prev << 16);  // h0(t-1)
        const bhalf* h0c = h0buf + ((size_t)tl << 16);    // h0(t)
        const bhalf* h1r = h1buf + ((size_t)prev << 16);  // h1(t-1)

        f32x4 acc[NMT];
        #pragma unroll
        for (int mt = 0; mt < NMT; ++mt) acc[mt] = zero4;

        if (IS_L0) {
            s8v bfr[32];
            #pragma unroll
            for (int ks = 0; ks < 32; ++ks)
                bfr[ks] = *(const s8v*)(h0r + batch * 1024 + (ks << 5) + koff);
            #pragma unroll
            for (int ks = 0; ks < 32; ++ks)
                #pragma unroll
                for (int mt = 0; mt < 4; ++mt) {
                    s8v a = *(const s8v*)&Wlds[((((mt << 5) + ks) << 6) + lane) << 3];
                    acc[mt] = __builtin_amdgcn_mfma_f32_16x16x32_bf16(a, bfr[ks], acc[mt], 0, 0, 0);
                }
        } else {
            // pass0: k 0..1023 from h0(t); pass1: k 1024..2047 from h1(t-1)
            s8v bfa[32], bfb[32];
            #pragma unroll
            for (int ks = 0; ks < 32; ++ks)
                bfa[ks] = *(const s8v*)(h0c + batch * 1024 + (ks << 5) + koff);
            #pragma unroll
            for (int ks = 0; ks < 32; ++ks)
                bfb[ks] = *(const s8v*)(h1r + batch * 1024 + (ks << 5) + koff);
            #pragma unroll
            for (int ks = 0; ks < 32; ++ks)
                #pragma unroll
                for (int mt = 0; mt < 2; ++mt) {
                    s8v a = *(const s8v*)&Wlds[((((mt << 6) + ks) << 6) + lane) << 3];
                    acc[mt] = __builtin_amdgcn_mfma_f32_16x16x32_bf16(a, bfa[ks], acc[mt], 0, 0, 0);
                }
            #pragma unroll
            for (int ks = 0; ks < 32; ++ks)
                #pragma unroll
                for (int mt = 0; mt < 2; ++mt) {
                    s8v a = *(const s8v*)&Wlds[((((mt << 6) + 32 + ks) << 6) + lane) << 3];
                    acc[mt] = __builtin_amdgcn_mfma_f32_16x16x32_bf16(a, bfb[ks], acc[mt], 0, 0, 0);
                }
        }

        // ---- register epilogue: all gates already lane-local ----
        float hvo[2];  // L1 out values kept for post-flag store
        if (IS_L0) {
            // acc[g][r] = gate g of h-col myhc+r, batch
            float hv[4];
            #pragma unroll
            for (int r = 0; r < 4; ++r) {
                float gi = acc[0][r] + g0elem(g0pre[0], r);
                float gf = acc[1][r] + g0elem(g0pre[1], r);
                float go = acc[2][r] + g0elem(g0pre[2], r);
                float gg = acc[3][r] + g0elem(g0pre[3], r);
                float cn = sigf(gf) * creg[r] + sigf(gi) * tanh_(gg);
                creg[r] = cn;
                hv[r] = sigf(go) * tanh_(cn);
            }
            u32x2 hp;
            hp.x = (unsigned)f2bf(hv[0]) | ((unsigned)f2bf(hv[1]) << 16);
            hp.y = (unsigned)f2bf(hv[2]) | ((unsigned)f2bf(hv[3]) << 16);
            unsigned long long hpu = __builtin_bit_cast(unsigned long long, hp);
            bhalf* hdst = h0buf + ((size_t)tl << 16) + (batch << 10) + myhc;
            __hip_atomic_store((unsigned long long*)hdst, hpu,
                               __ATOMIC_RELAXED, __HIP_MEMORY_SCOPE_AGENT);
        } else {
            // acc[mt][r]: gate (r&1)*2+mt, h-col myhc+(r>>1)
            #pragma unroll
            for (int j = 0; j < 2; ++j) {
                float gi = acc[0][2 * j]     + breg[0][j];
                float gf = acc[1][2 * j]     + breg[1][j];
                float go = acc[0][2 * j + 1] + breg[2][j];
                float gg = acc[1][2 * j + 1] + breg[3][j];
                float cn = sigf(gf) * creg[j] + sigf(gi) * tanh_(gg);
                creg[j] = cn;
                hvo[j] = sigf(go) * tanh_(cn);
            }
            unsigned hp = (unsigned)f2bf(hvo[0]) | ((unsigned)f2bf(hvo[1]) << 16);
            bhalf* hdst = h1buf + ((size_t)tl << 16) + (batch << 10) + myhc;
            __hip_atomic_store((unsigned*)hdst, hp,
                               __ATOMIC_RELAXED, __HIP_MEMORY_SCOPE_AGENT);
        }

        // publish: all h stores acked at the LLC, then flag (own cacheline)
        asm volatile("s_waitcnt vmcnt(0)" ::: "memory");
        __syncthreads();
        if (tid == 0)
            __hip_atomic_store(myflag, t + 1, __ATOMIC_RELAXED, __HIP_MEMORY_SCOPE_AGENT);
        // `out` is only read by the host at the end: HBM store after the flag
        if (!IS_L0) {
            f32x2 ov = {hvo[0], hvo[1]};
            *(f32x2*)(out + (((size_t)t * 64 + batch) << 10) + myhc) = ov;
        }
    }

    // persist c for next chunk / tail
    {
        float* cp = cws + ((size_t)batch << 10) + myhc;
        #pragma unroll
        for (int j = 0; j < NC; ++j) cp[j] = creg[j];
    }
}

__global__ __launch_bounds__(256, 1) void rec_k(
    const bhalf* __restrict__ W0T, const bhalf* __restrict__ W1T,
    const bhalf* __restrict__ G0, const float* __restrict__ bias1,
    bhalf* h0buf, bhalf* h1buf, float* c0ws, float* c1ws,
    int* done0, int* done1, float* out, int t0, int nsteps, int smask)
{
    __shared__ __align__(16) bhalf Wlds[65536];        // 128 KB swizzled weights
    const int tid = threadIdx.x;
    const int wg = blockIdx.x;
    if (wg < 64) {
        // layer0: 64 gate-cols; tile mt = gate, tile-row m = h-col (0..15)
        for (int it = 0; it < 32; ++it) {
            int e = (((it << 8) + tid) << 3);
            int ci = e >> 10, k0 = e & 1023;
            int n = ((ci >> 4) << 10) + (wg << 4) + (ci & 15);
            int mt = ci >> 4, m = ci & 15, ks = k0 >> 5, qk = (k0 >> 3) & 3;
            int off = ((((mt << 5) + ks) << 6) + (qk << 4) + m) << 3;
            *(s8v*)&Wlds[off] = *(const s8v*)(W0T + ((size_t)n << 10) + k0);
        }
        __syncthreads();
        rec_loop<true>(Wlds, G0, bias1, h0buf, h1buf, c0ws,
                       done0, done1, out, t0, nsteps, smask, wg);
    } else {
        int wg1 = wg - 64;
        // layer1: 32 gate-cols, K=2048. Row permutation for lane-local gates:
        // tile mt = g&1, tile-row m = hc*2 + (g>>1)  (hc 0..7 local)
        for (int it = 0; it < 32; ++it) {
            int e = (((it << 8) + tid) << 3);
            int ci = e >> 11, k0 = e & 2047;
            int g  = (ci >> 4) + ((ci & 1) << 1);
            int n  = (g << 10) + (wg1 << 3) + ((ci >> 1) & 7);
            int mt = ci >> 4, m = ci & 15, ks = k0 >> 5, qk = (k0 >> 3) & 3;
            int off = ((((mt << 6) + ks) << 6) + (qk << 4) + m) << 3;
            *(s8v*)&Wlds[off] = *(const s8v*)(W1T + ((size_t)n << 11) + k0);
        }
        __syncthreads();
        rec_loop<false>(Wlds, G0, bias1, h0buf, h1buf, c1ws,
                        done0, done1, out, t0, nsteps, smask, wg1);
    }
}

// --------------------------------- tail -------------------------------------
__global__ __launch_bounds__(256) void tail_k(
    const bhalf* __restrict__ h0f, const bhalf* __restrict__ h1f,
    const float* __restrict__ c0, const float* __restrict__ c1, float* dst)
{
    int i = blockIdx.x * 256 + threadIdx.x;  // grid 512 -> 131072
    if (i >= 131072) return;
    int l = i >> 16, r = i & 65535;
    dst[i] = bf2f(l ? h1f[r] : h0f[r]);
    dst[131072 + i] = l ? c1[r] : c0[r];
}

// --------------------------------- host -------------------------------------
extern "C" void kernel_launch(void* const* d_in, const int* in_sizes, int n_in,
                              void* d_out, int out_size, void* d_ws, size_t ws_size,
                              hipStream_t stream) {
    const float* x    = (const float*)d_in[0];
    const float* Wih0 = (const float*)d_in[1];
    const float* bih0 = (const float*)d_in[2];
    const float* Whh0 = (const float*)d_in[3];
    const float* bhh0 = (const float*)d_in[4];
    const float* Wih1 = (const float*)d_in[5];
    const float* bih1 = (const float*)d_in[6];
    const float* Whh1 = (const float*)d_in[7];
    const float* bhh1 = (const float*)d_in[8];
    float* out = (float*)d_out;
    char* ws = (char*)d_ws;

    bhalf* WT0ih = (bhalf*)(ws);                    // [4096][1024] bf16
    bhalf* WT0hh = (bhalf*)(ws + 8388608);          // [4096][1024]
    bhalf* WT1   = (bhalf*)(ws + 16777216);         // [4096][2048] = [Wih1;Whh1]
    float* bias0 = (float*)(ws + 33554432);
    float* bias1 = (float*)(ws + 33570816);
    float* c0    = (float*)(ws + 33587200);         // 64x1024 f32
    float* c1    = (float*)(ws + 33849344);
    int*   done0 = (int*)(ws + 34111488);           // 64 x 32 ints (128B apart)
    int*   done1 = (int*)(ws + 34119680);           // 128 x 32 ints
    const size_t fixedSz = 34136064;

    // per-step h slots: h0/h1 each CHUNK x 128KB; G0 CHUNK x 512KB
    int CHUNK = 8;
    for (int c = 512; c >= 8; c >>= 1)
        if (fixedSz + (size_t)c * (131072 + 131072 + 524288) <= ws_size) { CHUNK = c; break; }

    bhalf* h0buf = (bhalf*)(ws + fixedSz);
    bhalf* h1buf = (bhalf*)(ws + fixedSz + (size_t)CHUNK * 131072);
    bhalf* G0    = (bhalf*)(ws + fixedSz + (size_t)CHUNK * 262144);

    // zero the incoming-state slot (slot CHUNK-1 holds h(t0-1) at chunk start;
    // for t0=0 that must be zeros)
    init_k<<<256, 256, 0, stream>>>(bih0, bhh0, bih1, bhh1, bias0, bias1,
                                    h0buf + (size_t)(CHUNK - 1) * 65536,
                                    h1buf + (size_t)(CHUNK - 1) * 65536,
                                    c0, c1, done0);
    transpose_k<<<1024, 256, 0, stream>>>(Wih0, WT0ih, 1024, 0);
    transpose_k<<<1024, 256, 0, stream>>>(Whh0, WT0hh, 1024, 0);
    transpose_k<<<1024, 256, 0, stream>>>(Wih1, WT1, 2048, 0);
    transpose_k<<<1024, 256, 0, stream>>>(Whh1, WT1, 2048, 1024);

    for (int t0 = 0; t0 < 512; t0 += CHUNK) {
        int bmCount = CHUNK / 2;
        g0gemm_k<<<bmCount * 32, 256, 0, stream>>>(x, WT0ih, bias0, G0, t0, bmCount);
        rec_k<<<192, 256, 0, stream>>>(WT0hh, WT1, G0, bias1, h0buf, h1buf,
                                       c0, c1, done0, done1, out, t0, CHUNK, CHUNK - 1);
    }
    // final h: t=511 -> slot 511 % CHUNK == CHUNK-1 (512 is a multiple of CHUNK)
    tail_k<<<512, 256, 0, stream>>>(h0buf + (size_t)(CHUNK - 1) * 65536,
                                    h1buf + (size_t)(CHUNK - 1) * 65536,
                                    c0, c1, out + 33554432);
}